// Round 1
// baseline (966.911 us; speedup 1.0000x reference)
//
#include <hip/hip_runtime.h>

// ScaleLasryLions R3: per-scale 4-stage pipeline with h-fast transposed staging.
// closing = eroH(eroW(dilW(dilH x))), opening = dilH(dilW(eroW(eroH x)))
// (separable same-type passes commute => equals reference order).
//
// K1: x (interleaved) -> H-dil / H-ero, stored TRANSPOSED h-fast:
//     full tiles: buf[((p*FT+ty)*W + w)*32 + o]  (row = 32*ty+o, p = c*8+b)
//     tail (TR = HA-32*FT rows): buf[TAILOFF + (p*W + w)*TR + o]
//     Each thread writes one contiguous 128-B run straight from registers:
//     no LDS, no barriers, full-line stores (fixes 1.57x write amp + latency
//     stalls seen in rocprof on the old k_hpass1).
// K2: per (plane, h-tile): both W passes (dil+ero / ero+dil), expanded
//     intermediate in LDS, input reads are 128-B coalesced tile rows,
//     output planar [p][h'][w].
// K3: final H-pass + blend -> res planar (MODE 0 fused / 1 A-only / 2 B-accum)
// K4: res planar -> out interleaved (unchanged)
//
// Workspace tiers: T1 = 3 big buffers (134.5 MB), T2 = 2 + res (127.4 MB,
// proven available), else old fused fallback.

constexpr int BB = 8, HH = 192, WW = 192, CHN = 32, SCST = 128;

constexpr float s2_of(int si) { // scale^2 for {0.25,0.75,1.75,3.75}
    return si == 0 ? 0.0625f : si == 1 ? 0.5625f : si == 2 ? 3.0625f : 14.0625f;
}
constexpr int cdiv_(int a, int b) { return (a + b - 1) / b; }

// ---------------- K1: H-pass, register-direct transposed stores ----------------
// MODE: 0 = both (dil->A, ero->Bb), 1 = dil only ->A, 2 = ero only ->A
template <int SI, int SW, int MODE>
__launch_bounds__(256, 4) __global__
void k1_hpass(const float* __restrict__ x, const float* __restrict__ coef,
              float* __restrict__ A, float* __restrict__ Bb) {
    constexpr int L = 2 * SW + 1, HA = HH + 2 * SW, FT = HA / 32, TR = HA - 32 * FT;
    constexpr int WN = 32 + 2 * SW;
    constexpr size_t TAILOFF = (size_t)CHN * BB * FT * WW * 32;
    constexpr float S2 = s2_of(SI);
    const int tid = threadIdx.x;
    const int c = tid & 31, wl = tid >> 5;        // 32 c x 8 w
    const int w = blockIdx.x * 8 + wl;
    const int ty = blockIdx.y;
    const int b = blockIdx.z;
    const int r0 = ty * 32;
    const bool tail = (TR > 0) && (ty == FT);
    const float kmul = coef[c];
    const int p = c * BB + b;

    float wb[WN];
    const float* xb = x + ((size_t)b * HH * WW + w) * SCST + SI * CHN + c;
#pragma unroll
    for (int t = 0; t < WN; ++t) {
        int gh = r0 + t - 2 * SW;
        gh = gh < 0 ? 0 : (gh > HH - 1 ? HH - 1 : gh);
        wb[t] = xb[(size_t)gh * (WW * SCST)];
    }
    const size_t offF = (((size_t)p * FT + ty) * WW + w) * 32;
    const size_t offT = TAILOFF + ((size_t)p * WW + w) * TR;

    if (MODE != 2) { // dilation -> A
        float acc[32];
#pragma unroll
        for (int j = 0; j < L; ++j) {
            const float v = (float)(j - SW);
            const float tp = (-(v * v) / S2) * kmul;
#pragma unroll
            for (int o = 0; o < 32; ++o) {
                float t2 = wb[o + j] + tp;
                acc[o] = (j == 0) ? t2 : fmaxf(acc[o], t2);
            }
        }
        if (!tail) {
            float4* op = (float4*)(A + offF);
#pragma unroll
            for (int i = 0; i < 8; ++i)
                op[i] = make_float4(acc[4 * i], acc[4 * i + 1], acc[4 * i + 2], acc[4 * i + 3]);
        } else {
            float* op = A + offT;
#pragma unroll
            for (int o = 0; o < TR; ++o) op[o] = acc[o];
        }
    }
    if (MODE != 1) { // erosion -> Bb (MODE 0) or A (MODE 2)
        float acc[32];
#pragma unroll
        for (int j = 0; j < L; ++j) {
            const float v = (float)(j - SW);
            const float tp = (-(v * v) / S2) * kmul;
#pragma unroll
            for (int o = 0; o < 32; ++o) {
                float t2 = wb[o + j] - tp;
                acc[o] = (j == 0) ? t2 : fminf(acc[o], t2);
            }
        }
        float* dst = (MODE == 0) ? Bb : A;
        if (!tail) {
            float4* op = (float4*)(dst + offF);
#pragma unroll
            for (int i = 0; i < 8; ++i)
                op[i] = make_float4(acc[4 * i], acc[4 * i + 1], acc[4 * i + 2], acc[4 * i + 3]);
        } else {
            float* op = dst + offT;
#pragma unroll
            for (int o = 0; o < TR; ++o) op[o] = acc[o];
        }
    }
}

// ---------------- K2: both W-passes, tiled-transposed in -> planar out ----------
// BR 0 (closing, from dilH): dilW(+k) then eroW(-kc)
// BR 1 (opening, from eroH): eroW(-k) then dilW(+kc)
template <int SI, int SW, int BR>
__launch_bounds__(256, 4) __global__
void k2_wpass(const float* __restrict__ In, const float* __restrict__ coef,
              const float* __restrict__ cin, float* __restrict__ Out) {
    constexpr int L = 2 * SW + 1, HA = HH + 2 * SW, WE = WW + 2 * SW;
    constexpr int FT = HA / 32, TR = HA - 32 * FT;
    constexpr int NQ1 = cdiv_(WE, 8), NQ2 = WW / 8;
    constexpr int TMPR = NQ1 * 8;
    constexpr size_t TAILOFF = (size_t)CHN * BB * FT * WW * 32;
    constexpr float S2 = s2_of(SI);
    __shared__ float tmp[TMPR][33];
    const int tid = threadIdx.x;
    const int l = tid & 31, g = tid >> 5;         // 32 h-lanes x 8 w-groups
    const int ty = blockIdx.x;
    const int p = blockIdx.y;                      // c*8+b
    const int c = p >> 3;
    const bool tail = (TR > 0) && (ty == FT);
    const int nr = tail ? TR : 32;
    const int le = (l < nr) ? l : 0;               // keep OOB lanes in-bounds
    const int r0 = ty * 32;
    const int pitch = tail ? TR : 32;
    const float* tb = tail ? (In + TAILOFF + (size_t)p * WW * TR)
                           : (In + (((size_t)p * FT + ty) * (size_t)WW) * 32);
    const float k1 = coef[c], k2v = coef[c] * cin[c];

    { // pass 1: W (clamp-padded) -> WE, intermediate into LDS
        float wbuf[NQ1 + 2 * SW];
#pragma unroll
        for (int t = 0; t < NQ1 + 2 * SW; ++t) {
            int wi = g * NQ1 + t - 2 * SW;
            wi = wi < 0 ? 0 : (wi > WW - 1 ? WW - 1 : wi);
            wbuf[t] = tb[wi * pitch + le];
        }
        float acc[NQ1];
#pragma unroll
        for (int j = 0; j < L; ++j) {
            const float v = (float)(j - SW);
            const float tp = (-(v * v) / S2) * k1;
#pragma unroll
            for (int o = 0; o < NQ1; ++o) {
                float t2 = (BR == 0) ? wbuf[o + j] + tp : wbuf[o + j] - tp;
                acc[o] = (j == 0) ? t2 : ((BR == 0) ? fmaxf(acc[o], t2) : fminf(acc[o], t2));
            }
        }
#pragma unroll
        for (int o = 0; o < NQ1; ++o) tmp[g * NQ1 + o][l] = acc[o];
    }
    __syncthreads();
    { // pass 2: WE -> W (VALID), opposite op, taps kc; planar store
        float wbuf[NQ2 + 2 * SW];
#pragma unroll
        for (int t = 0; t < NQ2 + 2 * SW; ++t) wbuf[t] = tmp[g * NQ2 + t][l];
        float acc[NQ2];
#pragma unroll
        for (int j = 0; j < L; ++j) {
            const float v = (float)(j - SW);
            const float tp = (-(v * v) / S2) * k2v;
#pragma unroll
            for (int o = 0; o < NQ2; ++o) {
                float t2 = (BR == 0) ? wbuf[o + j] - tp : wbuf[o + j] + tp;
                acc[o] = (j == 0) ? t2 : ((BR == 0) ? fminf(acc[o], t2) : fmaxf(acc[o], t2));
            }
        }
        if (l < nr) {
            float* orow = Out + ((size_t)p * HA + r0 + l) * WW + g * NQ2;
#pragma unroll
            for (int i = 0; i < NQ2 / 4; ++i)
                ((float4*)orow)[i] = make_float4(acc[4 * i], acc[4 * i + 1], acc[4 * i + 2], acc[4 * i + 3]);
        }
    }
}

// ---------------- K3: final H-pass + blend -> res planar ----------------
// MODE 0: fused (res = av*eroH(A) + (1-av)*dilH(B))
// MODE 1: res  = av*eroH(A)
// MODE 2: res += (1-av)*dilH(B)
template <int SI, int SW, int MODE>
__launch_bounds__(256, 4) __global__
void k3_hpass(const float* __restrict__ A, const float* __restrict__ Bb,
              const float* __restrict__ coef, const float* __restrict__ cin,
              const float* __restrict__ ain, float* __restrict__ res) {
    constexpr int L = 2 * SW + 1, HA = HH + 2 * SW, RS = 64, RT = RS + 2 * SW;
    constexpr float S2 = s2_of(SI);
    __shared__ float tile[RT][64 + 1];
    const int tid = threadIdx.x;
    const int p = blockIdx.z;            // plane = c*8+b
    const int c = p >> 3;
    const int w0 = blockIdx.x * 64, r0 = blockIdx.y * RS;
    const float kc = coef[c] * cin[c], av = ain[c];
    const int wl = tid & 63, rq = tid >> 6; // 4 groups x 16 rows

    float xc[16];
    if (MODE != 2) {
        const float* Ab = A + ((size_t)p * HA + r0) * WW + w0;
        for (int i = tid; i < RT * 64; i += 256) {
            int r = i >> 6, w2 = i & 63;
            tile[r][w2] = Ab[(size_t)r * WW + w2];
        }
        __syncthreads();
        float wbuf[16 + 2 * SW];
#pragma unroll
        for (int t = 0; t < 16 + 2 * SW; ++t) wbuf[t] = tile[rq * 16 + t][wl];
#pragma unroll
        for (int j = 0; j < L; ++j) {
            const float v = (float)(j - SW);
            const float tp = (-(v * v) / S2) * kc;
#pragma unroll
            for (int o = 0; o < 16; ++o) {
                float t2 = wbuf[o + j] - tp; // erosion
                xc[o] = (j == 0) ? t2 : fminf(xc[o], t2);
            }
        }
        if (MODE == 0) __syncthreads();
    }
    float xo[16];
    if (MODE != 1) {
        const float* Bp = Bb + ((size_t)p * HA + r0) * WW + w0;
        for (int i = tid; i < RT * 64; i += 256) {
            int r = i >> 6, w2 = i & 63;
            tile[r][w2] = Bp[(size_t)r * WW + w2];
        }
        __syncthreads();
        float wbuf[16 + 2 * SW];
#pragma unroll
        for (int t = 0; t < 16 + 2 * SW; ++t) wbuf[t] = tile[rq * 16 + t][wl];
#pragma unroll
        for (int j = 0; j < L; ++j) {
            const float v = (float)(j - SW);
            const float tp = (-(v * v) / S2) * kc;
#pragma unroll
            for (int o = 0; o < 16; ++o) {
                float t2 = wbuf[o + j] + tp; // dilation
                xo[o] = (j == 0) ? t2 : fmaxf(xo[o], t2);
            }
        }
    }
    float* rp = res + ((size_t)p * HH + r0) * WW + w0;
#pragma unroll
    for (int o = 0; o < 16; ++o) {
        size_t idx = (size_t)(rq * 16 + o) * WW + wl;
        if (MODE == 0)      rp[idx] = av * xc[o] + (1.0f - av) * xo[o];
        else if (MODE == 1) rp[idx] = av * xc[o];
        else                rp[idx] = rp[idx] + (1.0f - av) * xo[o];
    }
}

// ---------------- K4: planar res -> interleaved out ----------------
template <int SI>
__launch_bounds__(256, 8) __global__
void k_scatter(const float* __restrict__ res, float* __restrict__ out) {
    __shared__ float stg[CHN][33];
    const int tid = threadIdx.x;
    const int w0 = blockIdx.x * 32, h = blockIdx.y, b = blockIdx.z;
#pragma unroll
    for (int it = 0; it < 4; ++it) {
        int cc = (tid >> 5) + it * 8, w = tid & 31;
        stg[cc][w] = res[((size_t)(cc * BB + b) * HH + h) * WW + w0 + w];
    }
    __syncthreads();
#pragma unroll
    for (int it = 0; it < 4; ++it) {
        int w = (tid >> 5) + it * 8, cc = tid & 31;
        out[((size_t)(b * HH + h) * WW + w0 + w) * SCST + SI * CHN + cc] = stg[cc][w];
    }
}

// ---------------- Fallback: R1 fused kernel (used if ws too small) ----------------
constexpr int r4_(int a) { return (a + 3) & ~3; }
constexpr int pickNH(int R, int C, int NT) {
    for (int nh = 1; nh <= R; ++nh)
        if (cdiv_(R, nh) * C <= NT) return nh;
    return R;
}
template <int L, int SW, int SI, bool DIL, int NH, int R, int PIT>
__device__ __forceinline__ void pass_compute_si(const float* __restrict__ in, int r0, int c,
                                                float kmul, float (&acc)[NH]) {
    constexpr float S2 = s2_of(SI);
    float wb[NH + L - 1];
#pragma unroll
    for (int t = 0; t < NH + L - 1; ++t) {
        int rr = r0 + t;
        if (rr > R + L - 2) rr = R + L - 2;
        wb[t] = in[rr * PIT + c];
    }
#pragma unroll
    for (int j = 0; j < L; ++j) {
        float v = (float)(j - SW);
        float tp = (-(v * v) / S2) * kmul;
#pragma unroll
        for (int o = 0; o < NH; ++o) {
            float t = DIL ? wb[o + j] + tp : wb[o + j] - tp;
            if (j == 0) acc[o] = t;
            else acc[o] = DIL ? fmaxf(acc[o], t) : fminf(acc[o], t);
        }
    }
}
template <int L, int SW, int SI, bool DIL, int NH, int R, int C, int PIT, int POUT, int NT>
__device__ __forceinline__ void pass_lds(const float* __restrict__ in, float* __restrict__ outT,
                                         float kmul, int tid) {
    constexpr int nseg = cdiv_(R, NH);
    for (int item = tid; item < nseg * C; item += NT) {
        int c = item % C, r0 = (item / C) * NH;
        float acc[NH];
        pass_compute_si<L, SW, SI, DIL, NH, R, PIT>(in, r0, c, kmul, acc);
#pragma unroll
        for (int o = 0; o < NH; ++o)
            if (r0 + o < R) outT[c * POUT + (r0 + o)] = acc[o];
    }
}
template <int SI, int SW, int TH, int TW, int NT, int MW>
__launch_bounds__(NT, MW) __global__
void lasry_kernel(const float* __restrict__ x, const float* __restrict__ coef,
                  const float* __restrict__ cin, const float* __restrict__ ain,
                  float* __restrict__ out) {
    constexpr int L = 2 * SW + 1;
    constexpr int IH = TH + 4 * SW, IW = TW + 4 * SW;
    constexpr int R1 = TH + 2 * SW, C1 = IW;
    constexpr int R2 = TW + 2 * SW, C2 = R1;
    constexpr int R3 = TH,          C3 = R2;
    constexpr int R4 = TW,          C4 = R3;
    constexpr int PIN = IW, PA = r4_(R1), PB = r4_(R2), PA2 = r4_(R3);
    constexpr int NH1 = pickNH(R1, C1, NT), NH2 = pickNH(R2, C2, NT);
    constexpr int NH3 = pickNH(R3, C3, NT), NH4 = pickNH(R4, C4, NT);
    __shared__ float smem[IH * PIN + C1 * PA + C2 * PB];
    float* bufIn = smem;
    float* A = smem + IH * PIN;
    float* B = A + C1 * PA;
    float* A2 = A;
    const int tid = threadIdx.x;
    const int b = blockIdx.z >> 5, ch = blockIdx.z & 31;
    const int h0 = blockIdx.y * TH, w0 = blockIdx.x * TW;
    const float kmul = coef[ch];
    const float kcmul = kmul * cin[ch];
    const float av = ain[ch];
    const float* xb = x + (size_t)(b * HH * WW) * SCST + SI * CHN + ch;
    constexpr int NLOAD = cdiv_(IH * IW, NT);
#pragma unroll
    for (int t = 0; t < NLOAD; ++t) {
        int idx = tid + t * NT;
        if (idx < IH * IW) {
            int r = idx / IW, c = idx - r * IW;
            int gh = min(max(h0 + r - 2 * SW, 0), HH - 1);
            int gw = min(max(w0 + c - 2 * SW, 0), WW - 1);
            bufIn[r * PIN + c] = xb[(size_t)(gh * WW + gw) * SCST];
        }
    }
    __syncthreads();
    const int c4 = tid % C4;
    const int r04 = (tid / C4) * NH4;
    const bool act4 = tid < cdiv_(R4, NH4) * C4;
    float xcv[NH4];
    pass_lds<L, SW, SI, true,  NH1, R1, C1, PIN, PA,  NT>(bufIn, A, kmul, tid);  __syncthreads();
    pass_lds<L, SW, SI, true,  NH2, R2, C2, PA,  PB,  NT>(A,     B, kmul, tid);  __syncthreads();
    pass_lds<L, SW, SI, false, NH3, R3, C3, PB,  PA2, NT>(B,    A2, kcmul, tid); __syncthreads();
    if (act4) pass_compute_si<L, SW, SI, false, NH4, R4, PA2>(A2, r04, c4, kcmul, xcv);
    __syncthreads();
    pass_lds<L, SW, SI, false, NH1, R1, C1, PIN, PA,  NT>(bufIn, A, kmul, tid);  __syncthreads();
    pass_lds<L, SW, SI, false, NH2, R2, C2, PA,  PB,  NT>(A,     B, kmul, tid);  __syncthreads();
    pass_lds<L, SW, SI, true,  NH3, R3, C3, PB,  PA2, NT>(B,    A2, kcmul, tid); __syncthreads();
    if (act4) {
        float xov[NH4];
        pass_compute_si<L, SW, SI, true, NH4, R4, PA2>(A2, r04, c4, kcmul, xov);
        const int h = h0 + c4;
        float* ob = out + ((size_t)(b * HH + h) * WW) * SCST + SI * CHN + ch;
#pragma unroll
        for (int o = 0; o < NH4; ++o) {
            int w = w0 + r04 + o;
            if (r04 + o < R4 && w < WW) ob[(size_t)w * SCST] = av * xcv[o] + (1.0f - av) * xov[o];
        }
    }
}

// ---------------- host ----------------
template <int SI, int SW>
static void run_t1(const float* x, const float* coef, const float* cv, const float* av,
                   float* out, float* At, float* Bt, float* A2, float* B2, float* res,
                   hipStream_t s) {
    constexpr int HA = HH + 2 * SW, FT = HA / 32, TR = HA - 32 * FT, NT = FT + (TR ? 1 : 0);
    k1_hpass<SI, SW, 0><<<dim3(WW / 8, NT, BB), 256, 0, s>>>(x, coef, At, Bt);
    k2_wpass<SI, SW, 0><<<dim3(NT, CHN * BB), 256, 0, s>>>(At, coef, cv, A2);
    k2_wpass<SI, SW, 1><<<dim3(NT, CHN * BB), 256, 0, s>>>(Bt, coef, cv, B2);
    k3_hpass<SI, SW, 0><<<dim3(WW / 64, HH / 64, CHN * BB), 256, 0, s>>>(A2, B2, coef, cv, av, res);
    k_scatter<SI><<<dim3(WW / 32, HH, BB), 256, 0, s>>>(res, out);
}
template <int SI, int SW>
static void run_t2(const float* x, const float* coef, const float* cv, const float* av,
                   float* out, float* R1, float* R2, float* res, hipStream_t s) {
    constexpr int HA = HH + 2 * SW, FT = HA / 32, TR = HA - 32 * FT, NT = FT + (TR ? 1 : 0);
    k1_hpass<SI, SW, 1><<<dim3(WW / 8, NT, BB), 256, 0, s>>>(x, coef, R1, nullptr);
    k2_wpass<SI, SW, 0><<<dim3(NT, CHN * BB), 256, 0, s>>>(R1, coef, cv, R2);
    k3_hpass<SI, SW, 1><<<dim3(WW / 64, HH / 64, CHN * BB), 256, 0, s>>>(R2, R2, coef, cv, av, res);
    k1_hpass<SI, SW, 2><<<dim3(WW / 8, NT, BB), 256, 0, s>>>(x, coef, R1, nullptr);
    k2_wpass<SI, SW, 1><<<dim3(NT, CHN * BB), 256, 0, s>>>(R1, coef, cv, R2);
    k3_hpass<SI, SW, 2><<<dim3(WW / 64, HH / 64, CHN * BB), 256, 0, s>>>(R2, R2, coef, cv, av, res);
    k_scatter<SI><<<dim3(WW / 32, HH, BB), 256, 0, s>>>(res, out);
}

extern "C" void kernel_launch(void* const* d_in, const int* in_sizes, int n_in,
                              void* d_out, int out_size, void* d_ws, size_t ws_size,
                              hipStream_t stream) {
    const float* x    = (const float*)d_in[0];
    const float* coef = (const float*)d_in[1];
    const float* cv   = (const float*)d_in[2];
    const float* av   = (const float*)d_in[3];
    float* out = (float*)d_out;
    (void)in_sizes; (void)n_in; (void)out_size;

    constexpr size_t TBUF  = (size_t)CHN * BB * (HH + 2 * 18) * WW;   // 11,206,656 floats (SI3 size)
    constexpr size_t RESSZ = (size_t)CHN * BB * HH * WW;              //  9,437,184 floats
    constexpr size_t T1_NEED = 3 * TBUF * sizeof(float);              // 134,479,872 B
    constexpr size_t T2_NEED = (2 * TBUF + RESSZ) * sizeof(float);    // 127,401,984 B (proven budget)

    float* W0 = (float*)d_ws;
    if (ws_size >= T1_NEED) {
        float* At = W0;
        float* Bt = W0 + TBUF;
        float* A2 = W0 + 2 * TBUF;
        float* B2 = W0;          // reuse At region (dead after k2a)
        float* res = W0 + TBUF;  // reuse Bt region (dead after k2b)
        run_t1<0, 1>(x, coef, cv, av, out, At, Bt, A2, B2, res, stream);
        run_t1<1, 3>(x, coef, cv, av, out, At, Bt, A2, B2, res, stream);
        run_t1<2, 8>(x, coef, cv, av, out, At, Bt, A2, B2, res, stream);
        run_t1<3, 18>(x, coef, cv, av, out, At, Bt, A2, B2, res, stream);
    } else if (ws_size >= T2_NEED) {
        float* R1 = W0;
        float* R2 = W0 + TBUF;
        float* res = W0 + 2 * TBUF;
        run_t2<0, 1>(x, coef, cv, av, out, R1, R2, res, stream);
        run_t2<1, 3>(x, coef, cv, av, out, R1, R2, res, stream);
        run_t2<2, 8>(x, coef, cv, av, out, R1, R2, res, stream);
        run_t2<3, 18>(x, coef, cv, av, out, R1, R2, res, stream);
    } else {
        // fallback: fused kernels (no workspace needed)
        lasry_kernel<0, 1, 64, 64, 1024, 8><<<dim3(3, 3, 256), 1024, 0, stream>>>(x, coef, cv, av, out);
        lasry_kernel<1, 3, 64, 64, 1024, 8><<<dim3(3, 3, 256), 1024, 0, stream>>>(x, coef, cv, av, out);
        lasry_kernel<2, 8, 64, 64, 1024, 4><<<dim3(3, 3, 256), 1024, 0, stream>>>(x, coef, cv, av, out);
        lasry_kernel<3, 18, 64, 48, 1024, 4><<<dim3(4, 3, 256), 1024, 0, stream>>>(x, coef, cv, av, out);
    }
}